// Round 13
// baseline (151.315 us; speedup 1.0000x reference)
//
#include <hip/hip_runtime.h>
#include <math.h>

#define DEP   96
#define HEADS 96
#define BSZ   16
#define DIM   512
#define REL   128
#define RELP  129   // REL + nil

typedef __attribute__((ext_vector_type(8))) _Float16  half8;    // 8 fp16 (4 VGPRs)
typedef __attribute__((ext_vector_type(2))) __fp16    fp16x2;   // cvt_pkrtz return type
typedef __attribute__((ext_vector_type(4))) float     floatx4;

__device__ __forceinline__ unsigned short f2h(float x) {
    union { _Float16 h; unsigned short u; } c;
    c.h = (_Float16)x;                                   // v_cvt_f16_f32 (RNE)
    return c.u;
}
// two f32 -> packed 2xf16 in one v_cvt_pkrtz_f16_f32
__device__ __forceinline__ unsigned pk_f2h(float a, float b) {
    union { fp16x2 h; unsigned u; } c;
    c.h = __builtin_amdgcn_cvt_pkrtz(a, b);
    return c.u;
}
// packed fp16 add / relu (VOP3P)
__device__ __forceinline__ unsigned pk_add_h2(unsigned a, unsigned b) {
    unsigned r; asm("v_pk_add_f16 %0, %1, %2" : "=v"(r) : "v"(a), "v"(b)); return r;
}
__device__ __forceinline__ unsigned pk_max_h2(unsigned a, unsigned b) {
    unsigned r; asm("v_pk_max_f16 %0, %1, %2" : "=v"(r) : "v"(a), "v"(b)); return r;
}
__device__ __forceinline__ half8 u4_to_h8(uint4 v) {
    union { uint4 u; half8 h; } c; c.u = v; return c.h;
}

#define PSS 72   // proj LDS row stride (fp16 elems): 144 B, 16B-aligned rows

// ---------------------------------------------------------------------------
// Kernel A: projections via fp16 MFMA (R5 shape).
//   z=0: P1[m][n] = outs@Wt[:, :512]^T + bt     (f32, row-major)
//   z=1: P2F = graph@Wt[:, 512:]^T, written in A-FRAGMENT ORDER, b-major:
//        P2F[(((b*16 + kk)*6 + mq)*64 + (l15 + ksl*16))*8 + e]
//          = proj value at graph-row h = mq*16+l15, batch b, k = kk*32+ksl*8+e
//        so fused's A-fragment load is a lane-linear global_load_dwordx4.
// Prelude (first 32 blocks): cast Wp -> WpF in B-fragment order (R11).
// ---------------------------------------------------------------------------
__global__ __launch_bounds__(256) void proj_kernel(
    const float* __restrict__ outs, const float* __restrict__ graph,
    const float* __restrict__ Wt, const float* __restrict__ bt,
    const float* __restrict__ Wp,
    float* __restrict__ P1, unsigned short* __restrict__ P2F,
    unsigned short* __restrict__ WpF)
{
    // ---- Wp f32 -> fp16 B-fragment-order prelude: 32 blocks x 256 thr ----
    {
        const int fb = (blockIdx.z * gridDim.y + blockIdx.y) * gridDim.x + blockIdx.x;
        if (fb < 32) {
            const int c    = fb * 256 + (int)threadIdx.x;    // 0..8191 chunks
            const int ln   = c & 63;
            const int nq   = (c >> 6) & 7;                   // nh*4 + nt
            const int kk   = c >> 9;                         // kti*2 + ks, 0..15
            const int row  = (nq >> 2) * 64 + (nq & 3) * 16 + (ln & 15);
            const int col  = kk * 32 + ((ln >> 4) & 3) * 8;
            const float* src = Wp + (size_t)row * DIM + col;
            float4 a = *(const float4*)src;
            float4 b = *(const float4*)(src + 4);
            uint4 o;
            o.x = pk_f2h(a.x, a.y); o.y = pk_f2h(a.z, a.w);
            o.z = pk_f2h(b.x, b.y); o.w = pk_f2h(b.z, b.w);
            *(uint4*)(WpF + (size_t)c * 8) = o;
        }
    }

    const int z = blockIdx.z;
    const float* A = z ? graph : outs;
    const int off  = z ? DIM : 0;
    const int row0 = blockIdx.y * 32;
    const int col0 = blockIdx.x * 64;

    __shared__ __align__(16) unsigned short As[32 * PSS];   // [m][k] fp16
    __shared__ __align__(16) unsigned short Ws[64 * PSS];   // [n][k] fp16

    const int tid  = threadIdx.x;
    const int lane = tid & 63;
    const int wv   = tid >> 6;          // 0..3
    const int ln15 = lane & 15;
    const int quad = lane >> 4;
    const int mh   = wv & 1;            // m-half: rows [16*mh, 16*mh+16)
    const int nh   = wv >> 1;           // n-half: cols [32*nh, 32*nh+32)

    floatx4 acc[2];
    acc[0] = (floatx4){0.f,0.f,0.f,0.f};
    acc[1] = (floatx4){0.f,0.f,0.f,0.f};

    for (int kt = 0; kt < DIM; kt += 64) {
        // A: f32 load + packed RTZ cast to fp16 LDS (1 slot/thread)
        {
            const int r  = tid >> 3;            // 0..31
            const int e8 = (tid & 7) * 8;
            const float* p = A + (size_t)(row0 + r) * DIM + kt + e8;
            float4 va = *(const float4*)p;
            float4 vb = *(const float4*)(p + 4);
            uint4 o;
            o.x = pk_f2h(va.x, va.y); o.y = pk_f2h(va.z, va.w);
            o.z = pk_f2h(vb.x, vb.y); o.w = pk_f2h(vb.z, vb.w);
            *(uint4*)&As[r * PSS + e8] = o;
        }
        // Wt: f32 load + cast (2 slots/thread)
        #pragma unroll
        for (int q = 0; q < 2; ++q) {
            const int slot = q*256 + tid;       // 0..511
            const int r  = slot >> 3;           // 0..63
            const int e8 = (slot & 7) * 8;
            const float* p = Wt + (size_t)(col0 + r) * (2*DIM) + off + kt + e8;
            float4 va = *(const float4*)p;
            float4 vb = *(const float4*)(p + 4);
            uint4 o;
            o.x = pk_f2h(va.x, va.y); o.y = pk_f2h(va.z, va.w);
            o.z = pk_f2h(vb.x, vb.y); o.w = pk_f2h(vb.z, vb.w);
            *(uint4*)&Ws[r * PSS + e8] = o;
        }
        __syncthreads();
        #pragma unroll
        for (int ks = 0; ks < 64; ks += 32) {
            half8 af = *(const half8*)&As[(mh*16 + ln15) * PSS + ks + quad*8];
            #pragma unroll
            for (int nt = 0; nt < 2; ++nt) {
                half8 bf8 = *(const half8*)&Ws[(nh*32 + nt*16 + ln15) * PSS + ks + quad*8];
                acc[nt] = __builtin_amdgcn_mfma_f32_16x16x32_f16(af, bf8, acc[nt], 0, 0, 0);
            }
        }
        __syncthreads();
    }

    #pragma unroll
    for (int nt = 0; nt < 2; ++nt) {
        #pragma unroll
        for (int reg = 0; reg < 4; ++reg) {
            const int m = row0 + mh*16 + quad*4 + reg;
            const int n = col0 + nh*32 + nt*16 + ln15;
            float v = acc[nt][reg];
            if (!z) {
                P1[(size_t)m * DIM + n] = v + bt[n];
            } else {
                // scatter into A-fragment order (1.5 MB total, L2-absorbed)
                const int h   = m >> 4, bb = m & 15;
                const int kk  = n >> 5, ksl = (n >> 3) & 3, e = n & 7;
                const int mq  = h >> 4, l15 = h & 15;
                P2F[((((size_t)bb*16 + kk)*6 + mq)*64 + l15 + ksl*16)*8 + e] = f2h(v);
            }
        }
    }
}

// ---------------------------------------------------------------------------
// Kernel B: fused pairwise relu + fp16-MFMA GEMM + log_softmax(129).
// R13: ZERO-BARRIER K-LOOP. 12-round ledger: occupancy (R6/7/9/10), staging
// bandwidth (R3/11), stores (R4), tiles (R9/10), barrier count (R12) all
// falsified — the remaining hypothesis is the stage/barrier pipeline ITSELF.
// Here both operands come fragment-direct from L2 (P2F for A, WpF for B,
// lane-linear 16 B/lane), relu is applied in-register (each A-element is
// consumed by exactly one fragment per block, so no redundant VALU), and
// the K-loop has NO __syncthreads and NO LDS tiles. drowH (1 KB) is staged
// once before the loop; dk reads are broadcast ds_read_b128 (conflict-free).
// LDS ~3 KB; (256,4); #pragma unroll 1 on kti caps load-hoisting (R2 spill
// lesson). Accumulation order identical to R4-R12 -> bit-identical output.
// ---------------------------------------------------------------------------
__global__ __launch_bounds__(256, 4) void fused_kernel(
    const float* __restrict__ P1, const unsigned short* __restrict__ P2F,
    const unsigned short* __restrict__ WpF, const float* __restrict__ bp,
    float* __restrict__ out)
{
    const int db = blockIdx.x;      // d*16 + b
    const int b  = db & 15;

    __shared__ __align__(16) unsigned short drowH[DIM];     // dep row fp16
    __shared__ float pmx[96][2];     // softmax partials per (row, col-half)
    __shared__ float pl [96][2];
    __shared__ float lseS[96];       // per-row lse

    const int tid  = threadIdx.x;       // 0..255
    const int lane = tid & 63;
    const int wv   = tid >> 6;          // 0..3
    const int ln15 = lane & 15;
    const int quad = lane >> 4;
    const int mh   = wv & 1;            // row half: [48*mh, 48*mh+48)
    const int nh   = wv >> 1;           // col half: [64*nh, 64*nh+64)

    // dep row f32 -> fp16 (one-time; the only pre-loop barrier)
    {
        float2 v = *(const float2*)(P1 + (size_t)db * DIM + tid*2);
        *(unsigned*)&drowH[tid*2] = pk_f2h(v.x, v.y);
    }
    __syncthreads();

    floatx4 acc[3][4];
    #pragma unroll
    for (int i = 0; i < 3; ++i)
        #pragma unroll
        for (int j = 0; j < 4; ++j) acc[i][j] = (floatx4){0.f,0.f,0.f,0.f};

    // per-b A-fragment base: 96 KB contiguous chunk of P2F
    const unsigned short* p2b = P2F + (size_t)b * (16*6*64*8);

    #pragma unroll 1
    for (int kti = 0; kti < 8; ++kti) {
        #pragma unroll
        for (int ks = 0; ks < 2; ++ks) {
            const int kk = kti*2 + ks;
            // drow fragment: broadcast ds_read_b128 (16 lanes same addr)
            uint4 dk = *(const uint4*)&drowH[kti*64 + ks*32 + quad*8];
            // A fragments: lane-linear L2 loads + in-register relu
            half8 af[3];
            #pragma unroll
            for (int mt = 0; mt < 3; ++mt) {
                uint4 pa = *(const uint4*)(p2b +
                    ((size_t)(kk*6 + mh*3 + mt)*64 + lane) * 8);
                uint4 o;
                o.x = pk_max_h2(pk_add_h2(pa.x, dk.x), 0u);
                o.y = pk_max_h2(pk_add_h2(pa.y, dk.y), 0u);
                o.z = pk_max_h2(pk_add_h2(pa.z, dk.z), 0u);
                o.w = pk_max_h2(pk_add_h2(pa.w, dk.w), 0u);
                af[mt] = u4_to_h8(o);
            }
            // B fragments: lane-linear L2 loads (R11/R12 path, verified)
            half8 bf[4];
            #pragma unroll
            for (int nt = 0; nt < 4; ++nt)
                bf[nt] = *(const half8*)(WpF +
                    (size_t)((kk*8 + nh*4 + nt)*64 + lane) * 8);
            #pragma unroll
            for (int nt = 0; nt < 4; ++nt)
                #pragma unroll
                for (int mt = 0; mt < 3; ++mt)
                    acc[mt][nt] = __builtin_amdgcn_mfma_f32_16x16x32_f16(
                        af[mt], bf[nt], acc[mt][nt], 0, 0, 0);
        }
    }

    // ---- epilogue phase 1: per-quadrant softmax partials (no nil yet) ----
    float bpv[4];
    #pragma unroll
    for (int nt = 0; nt < 4; ++nt) bpv[nt] = bp[nh*64 + nt*16 + ln15];

    #pragma unroll
    for (int mt = 0; mt < 3; ++mt) {
        #pragma unroll
        for (int reg = 0; reg < 4; ++reg) {
            const int m = mh*48 + mt*16 + quad*4 + reg;
            float s[4];
            #pragma unroll
            for (int nt = 0; nt < 4; ++nt) s[nt] = acc[mt][nt][reg] + bpv[nt];
            float mx = fmaxf(fmaxf(s[0], s[1]), fmaxf(s[2], s[3]));
            #pragma unroll
            for (int msk = 1; msk < 16; msk <<= 1) mx = fmaxf(mx, __shfl_xor(mx, msk));
            float l = 0.f;
            #pragma unroll
            for (int nt = 0; nt < 4; ++nt) l += __expf(s[nt] - mx);
            #pragma unroll
            for (int msk = 1; msk < 16; msk <<= 1) l += __shfl_xor(l, msk);
            if (ln15 == 0) { pmx[m][nh] = mx; pl[m][nh] = l; }
        }
    }
    __syncthreads();

    // ---- phase 1.5: lse once per row ----
    if (tid < 96) {
        const float mx0 = pmx[tid][0], mx1 = pmx[tid][1];
        const float MX = fmaxf(fmaxf(mx0, mx1), 0.f);   // nil = 0 in max
        const float L  = pl[tid][0] * __expf(mx0 - MX) + pl[tid][1] * __expf(mx1 - MX)
                       + __expf(-MX);                    // nil term
        lseS[tid] = MX + __logf(L);
    }
    __syncthreads();

    // ---- phase 2: direct stores ----
    #pragma unroll
    for (int mt = 0; mt < 3; ++mt) {
        #pragma unroll
        for (int reg = 0; reg < 4; ++reg) {
            const int m = mh*48 + mt*16 + quad*4 + reg;
            const float lse = lseS[m];
            const size_t base = ((size_t)db * HEADS + m) * RELP;
            #pragma unroll
            for (int nt = 0; nt < 4; ++nt)
                out[base + 1 + nh*64 + nt*16 + ln15] = acc[mt][nt][reg] + bpv[nt] - lse;
            if (nh == 0 && ln15 == 0) out[base] = -lse;
        }
    }
}

extern "C" void kernel_launch(void* const* d_in, const int* in_sizes, int n_in,
                              void* d_out, int out_size, void* d_ws, size_t ws_size,
                              hipStream_t stream) {
    const float* outs  = (const float*)d_in[0];
    const float* graph = (const float*)d_in[1];
    const float* Wt    = (const float*)d_in[2];
    const float* bt    = (const float*)d_in[3];
    const float* Wp    = (const float*)d_in[4];
    const float* bp    = (const float*)d_in[5];
    float* out = (float*)d_out;

    // Workspace: 4,849,664 B (P2F replaces P2H, same size).
    float* P1           = (float*)d_ws;                     // [1536][512] f32   (3 MB)
    unsigned short* P2F = (unsigned short*)(P1 + 786432);   // A-frag order      (1.5 MB)
    unsigned short* WpF = P2F + 786432;                     // B-frag order      (128 KB)

    proj_kernel<<<dim3(DIM/64, (DEP*BSZ)/32, 2), 256, 0, stream>>>(
        outs, graph, Wt, bt, Wp, P1, P2F, WpF);
    fused_kernel<<<DEP*BSZ, 256, 0, stream>>>(P1, P2F, WpF, bp, out);
}